// Round 1
// baseline (88.758 us; speedup 1.0000x reference)
//
#include <hip/hip_runtime.h>

#define W 4096
#define H 4096
#define BC 256      // output columns per block (== blockDim.x)
#define SR 64       // output rows per block strip
#define LW 272      // BC + 2*8 column halo
#define RAD 7       // max radius (k=15)

__global__ __launch_bounds__(256) void multibox_kernel(
    const float* __restrict__ x, const float* __restrict__ base,
    float* __restrict__ out)
{
    __shared__ float rowbuf[2][LW];

    const int t  = threadIdx.x;
    const int c0 = blockIdx.x * BC;
    const int i0 = blockIdx.y * SR;
    const int i1 = i0 + SR;
    const int j  = c0 + t;

    // weights 1/(7*k^2)
    const float w3  = 1.f/(7.f*9.f);
    const float w5  = 1.f/(7.f*25.f);
    const float w7  = 1.f/(7.f*49.f);
    const float w9  = 1.f/(7.f*81.f);
    const float w11 = 1.f/(7.f*121.f);
    const float w13 = 1.f/(7.f*169.f);
    const float w15 = 1.f/(7.f*225.f);

    // pending output accumulators: pend[q] <-> output row (r - 7 + q)
    float pend[15];
#pragma unroll
    for (int q = 0; q < 15; ++q) pend[q] = 0.f;

    auto stage = [&](int r, int slot) {
        int rc = min(max(r, 0), H - 1);
        const float* rowp = x + (size_t)rc * W;
        int c = c0 - 8 + t;
        c = min(max(c, 0), W - 1);
        rowbuf[slot][t] = rowp[c];
        if (t < 16) {
            int c2 = c0 + 248 + t;          // positions 256..271 of the padded row
            c2 = min(max(c2, 0), W - 1);
            rowbuf[slot][256 + t] = rowp[c2];
        }
    };

    stage(i0 - RAD, 0);
    __syncthreads();
    int slot = 0;

    for (int r = i0 - RAD; r <= i1 + RAD - 1; ++r) {
        // prefetch next row into the other slot (overlaps with compute below)
        if (r < i1 + RAD - 1) stage(r + 1, slot ^ 1);

        // horizontal ring sums from staged row
        const float* p = &rowbuf[slot][t + 8];
        float am7 = p[-7], am6 = p[-6], am5 = p[-5], am4 = p[-4];
        float am3 = p[-3], am2 = p[-2], am1 = p[-1];
        float a0 = p[0], a1 = p[1], a2 = p[2], a3 = p[3];
        float a4 = p[4], a5 = p[5], a6 = p[6], a7 = p[7];

        float s3  = am1 + a0 + a1;
        float s5  = s3  + am2 + a2;
        float s7  = s5  + am3 + a3;
        float s9  = s7  + am4 + a4;
        float s11 = s9  + am5 + a5;
        float s13 = s11 + am6 + a6;
        float s15 = s13 + am7 + a7;

        // suffix sums: cum[m] = sum over k with p_k >= m of w_k * s_k
        float c7 = w15 * s15;
        float c6 = c7 + w13 * s13;
        float c5 = c6 + w11 * s11;
        float c4 = c5 + w9  * s9;
        float c3 = c4 + w7  * s7;
        float c2v = c3 + w5 * s5;
        float c1 = c2v + w3 * s3;   // also cum[0]

        // pend[q] += cum[|q-7|]
        pend[0]  += c7;  pend[1]  += c6;  pend[2]  += c5;  pend[3]  += c4;
        pend[4]  += c3;  pend[5]  += c2v; pend[6]  += c1;  pend[7]  += c1;
        pend[8]  += c1;  pend[9]  += c2v; pend[10] += c3;  pend[11] += c4;
        pend[12] += c5;  pend[13] += c6;  pend[14] += c7;

        // output row r-7 is now complete
        if (r >= i0 + RAD) {
            int o = r - RAD;
            size_t idx = (size_t)o * W + j;
            out[idx] = pend[0] * base[idx];
        }

        // shift register (static indices -> stays in VGPRs)
#pragma unroll
        for (int q = 0; q < 14; ++q) pend[q] = pend[q + 1];
        pend[14] = 0.f;

        __syncthreads();
        slot ^= 1;
    }
}

extern "C" void kernel_launch(void* const* d_in, const int* in_sizes, int n_in,
                              void* d_out, int out_size, void* d_ws, size_t ws_size,
                              hipStream_t stream) {
    const float* x    = (const float*)d_in[0];
    const float* base = (const float*)d_in[1];
    float* out        = (float*)d_out;

    dim3 grid(W / BC, H / SR);
    multibox_kernel<<<grid, dim3(256), 0, stream>>>(x, base, out);
}

// Round 2
// 58.677 us; speedup vs baseline: 1.5127x; 1.5127x over previous
//
#include <hip/hip_runtime.h>

#define W 4096
#define H 4096
#define NT 256
#define VPC 4
#define COLS (NT * VPC)          // 1024 columns per block
#define SR 32                    // output rows per block strip
#define GROUP 4                  // rows staged per barrier
#define NSTAGE (SR + 14)         // 46 rows contribute to a strip
#define NG ((NSTAGE + GROUP - 1) / GROUP)   // 12 groups (48 staged, 46 used)
#define LW (COLS + 16)           // 1040 floats per staged row (8-col halo each side)
#define RAD 7

__global__ __launch_bounds__(NT) void multibox_kernel(
    const float* __restrict__ x, const float* __restrict__ base,
    float* __restrict__ out)
{
    __shared__ float buf[2][GROUP][LW];   // 33,280 B

    const int t  = threadIdx.x;
    const int c0 = blockIdx.x * COLS;
    const int i0 = blockIdx.y * SR;

    const float w3  = 1.f/(7.f*9.f);
    const float w5  = 1.f/(7.f*25.f);
    const float w7  = 1.f/(7.f*49.f);
    const float w9  = 1.f/(7.f*81.f);
    const float w11 = 1.f/(7.f*121.f);
    const float w13 = 1.f/(7.f*169.f);
    const float w15 = 1.f/(7.f*225.f);

    // clamped float4 load (edge-replicate); interior path is one global_load_dwordx4
    auto ld4 = [&](const float* __restrict__ rowp, int c) -> float4 {
        if (c >= 0 && c <= W - 4) return *(const float4*)(rowp + c);
        float4 v;
        v.x = rowp[min(max(c    , 0), W - 1)];
        v.y = rowp[min(max(c + 1, 0), W - 1)];
        v.z = rowp[min(max(c + 2, 0), W - 1)];
        v.w = rowp[min(max(c + 3, 0), W - 1)];
        return v;
    };

    float4 mreg[GROUP];   // main chunk per staged row
    float4 ereg[GROUP];   // extra halo chunk (threads 0..3 only)

    auto load_group = [&](int g) {
        const int rb = i0 - RAD + g * GROUP;
#pragma unroll
        for (int rr = 0; rr < GROUP; ++rr) {
            const int rc = min(max(rb + rr, 0), H - 1);
            const float* rowp = x + (size_t)rc * W;
            mreg[rr] = ld4(rowp, c0 - 8 + 4 * t);
            if (t < 4) ereg[rr] = ld4(rowp, c0 + 1016 + 4 * t);
        }
    };

    auto write_group = [&](int b) {
#pragma unroll
        for (int rr = 0; rr < GROUP; ++rr) {
            *(float4*)&buf[b][rr][4 * t] = mreg[rr];
            if (t < 4) *(float4*)&buf[b][rr][1024 + 4 * t] = ereg[rr];
        }
    };

    // pending output accumulators per owned column
    float pend[VPC][15];
#pragma unroll
    for (int m = 0; m < VPC; ++m)
#pragma unroll
        for (int q = 0; q < 15; ++q) pend[m][q] = 0.f;

    auto compute_group = [&](int b, int g) {
#pragma unroll
        for (int rr = 0; rr < GROUP; ++rr) {
            const int idx = g * GROUP + rr;          // staged-row index, uniform
            const float* p = &buf[b][rr][4 * t];     // floats 4t .. 4t+19

            float q[20];
            float4 v0 = *(const float4*)(p);
            float4 v1 = *(const float4*)(p + 4);
            float4 v2 = *(const float4*)(p + 8);
            float4 v3 = *(const float4*)(p + 12);
            float4 v4 = *(const float4*)(p + 16);
            q[0]=v0.x; q[1]=v0.y; q[2]=v0.z; q[3]=v0.w;
            q[4]=v1.x; q[5]=v1.y; q[6]=v1.z; q[7]=v1.w;
            q[8]=v2.x; q[9]=v2.y; q[10]=v2.z; q[11]=v2.w;
            q[12]=v3.x; q[13]=v3.y; q[14]=v3.z; q[15]=v3.w;
            q[16]=v4.x; q[17]=v4.y; q[18]=v4.z; q[19]=v4.w;

            float s3, s5, s7, s9, s11, s13, s15;
#pragma unroll
            for (int m = 0; m < VPC; ++m) {
                if (m == 0) {
                    s3  = q[7] + q[8] + q[9];
                    s5  = s3  + q[6] + q[10];
                    s7  = s5  + q[5] + q[11];
                    s9  = s7  + q[4] + q[12];
                    s11 = s9  + q[3] + q[13];
                    s13 = s11 + q[2] + q[14];
                    s15 = s13 + q[1] + q[15];
                } else {
                    s3  += q[9  + m] - q[6 + m];
                    s5  += q[10 + m] - q[5 + m];
                    s7  += q[11 + m] - q[4 + m];
                    s9  += q[12 + m] - q[3 + m];
                    s11 += q[13 + m] - q[2 + m];
                    s13 += q[14 + m] - q[1 + m];
                    s15 += q[15 + m] - q[m];
                }
                float c7 = w15 * s15;
                float c6 = c7 + w13 * s13;
                float c5 = c6 + w11 * s11;
                float c4 = c5 + w9  * s9;
                float c3 = c4 + w7  * s7;
                float c2 = c3 + w5  * s5;
                float c1 = c2 + w3  * s3;
                pend[m][0]  += c7; pend[m][1]  += c6; pend[m][2]  += c5;
                pend[m][3]  += c4; pend[m][4]  += c3; pend[m][5]  += c2;
                pend[m][6]  += c1; pend[m][7]  += c1; pend[m][8]  += c1;
                pend[m][9]  += c2; pend[m][10] += c3; pend[m][11] += c4;
                pend[m][12] += c5; pend[m][13] += c6; pend[m][14] += c7;
            }

            // staged row idx completes output row o = i0 + idx - 14
            if (idx >= 14 && idx < 14 + SR) {
                const int o = i0 + idx - 14;
                const size_t bi = (size_t)o * W + c0 + 4 * t;
                float4 bm = *(const float4*)(base + bi);
                float4 ov;
                ov.x = pend[0][0] * bm.x;
                ov.y = pend[1][0] * bm.y;
                ov.z = pend[2][0] * bm.z;
                ov.w = pend[3][0] * bm.w;
                *(float4*)(out + bi) = ov;
            }

            // shift registers (all-static indices)
#pragma unroll
            for (int m = 0; m < VPC; ++m) {
#pragma unroll
                for (int q2 = 0; q2 < 14; ++q2) pend[m][q2] = pend[m][q2 + 1];
                pend[m][14] = 0.f;
            }
        }
    };

    // prologue: stage group 0
    load_group(0);
    write_group(0);
    __syncthreads();

    for (int g = 0; g < NG - 1; ++g) {
        load_group(g + 1);          // issue next group's global loads early
        compute_group(g & 1, g);    // compute current group (hides load latency)
        write_group((g + 1) & 1);   // land prefetched rows in the other buffer
        __syncthreads();
    }
    compute_group((NG - 1) & 1, NG - 1);
}

extern "C" void kernel_launch(void* const* d_in, const int* in_sizes, int n_in,
                              void* d_out, int out_size, void* d_ws, size_t ws_size,
                              hipStream_t stream) {
    const float* x    = (const float*)d_in[0];
    const float* base = (const float*)d_in[1];
    float* out        = (float*)d_out;

    dim3 grid(W / COLS, H / SR);   // (4, 128) = 512 blocks
    multibox_kernel<<<grid, dim3(NT), 0, stream>>>(x, base, out);
}